// Round 5
// baseline (2091.830 us; speedup 1.0000x reference)
//
#include <hip/hip_runtime.h>
#include <math.h>

#define NROW 32768
#define DIM  1024
#define PDIM 256
#define NSEC 4
#define NCODE 1024
#define SECD 64

// ============================================================================
// K1: proj = (X + bias) @ W  (fp32, exact OpenBLAS order via K-split):
// blockIdx.z selects KC block {0..383 | 384..767 | 768..1023}; each C element
// is one ascending-k fmaf chain (bit-identical to the single-kernel version).
// k_combine applies the exact fold ((S0+S1)+S2) afterwards.
// 128x128 tile, 256 thr, 8x8 micro, register prefetch, fused xn2 (cb==0).
// ============================================================================
__global__ __launch_bounds__(256, 4) void k_proj_split(const float* __restrict__ X,
                                                       const float* __restrict__ W,
                                                       const float* __restrict__ bias,
                                                       float* __restrict__ S0,
                                                       float* __restrict__ S1,
                                                       float* __restrict__ S2,
                                                       float* __restrict__ xn2) {
    __shared__ float As[16][128];   // As[k][row]
    __shared__ float Bs[16][128];   // Bs[k][col]
    const int t = threadIdx.x;
    const int ry = t >> 4;          // rows ry*8..+7
    const int rx = t & 15;          // cols rx*8..+7
    const int rb = blockIdx.y * 128;
    const int cb = blockIdx.x * 128;
    const int zi = blockIdx.z;
    const int k0 = zi * 384;
    const int klen = (zi == 2) ? 256 : 384;
    float* __restrict__ dst = (zi == 0) ? S0 : (zi == 1 ? S1 : S2);
    const int lr = t >> 1;          // A stage row 0..127
    const int lk = (t & 1) * 8;     // A stage k offset
    const int bk = t >> 4;          // B stage k 0..15
    const int bc = (t & 15) * 8;    // B stage col
    const bool do_xn = (cb == 0);
    float acc[8][8] = {};
    float xsum = 0.0f;
    float4 a0, a1, b0, b1;
    {   // initial prefetch (kc = 0)
        const float* xp = &X[(size_t)(rb + lr) * DIM + k0 + lk];
        a0 = *(const float4*)xp;
        a1 = *(const float4*)(xp + 4);
        float4 c0 = *(const float4*)&bias[k0 + lk];
        float4 c1 = *(const float4*)&bias[k0 + lk + 4];
        a0.x += c0.x; a0.y += c0.y; a0.z += c0.z; a0.w += c0.w;
        a1.x += c1.x; a1.y += c1.y; a1.z += c1.z; a1.w += c1.w;
        b0 = *(const float4*)&W[(size_t)(k0 + bk) * PDIM + cb + bc];
        b1 = *(const float4*)&W[(size_t)(k0 + bk) * PDIM + cb + bc + 4];
    }
    for (int kc = 0; kc < klen; kc += 16) {
        As[lk + 0][lr] = a0.x; As[lk + 1][lr] = a0.y; As[lk + 2][lr] = a0.z; As[lk + 3][lr] = a0.w;
        As[lk + 4][lr] = a1.x; As[lk + 5][lr] = a1.y; As[lk + 6][lr] = a1.z; As[lk + 7][lr] = a1.w;
        *(float4*)&Bs[bk][bc] = b0;
        *(float4*)&Bs[bk][bc + 4] = b1;
        if (do_xn) {   // tolerant-path row-norm partial (uses staged regs)
            xsum = fmaf(a0.x, a0.x, xsum); xsum = fmaf(a0.y, a0.y, xsum);
            xsum = fmaf(a0.z, a0.z, xsum); xsum = fmaf(a0.w, a0.w, xsum);
            xsum = fmaf(a1.x, a1.x, xsum); xsum = fmaf(a1.y, a1.y, xsum);
            xsum = fmaf(a1.z, a1.z, xsum); xsum = fmaf(a1.w, a1.w, xsum);
        }
        __syncthreads();
        if (kc + 16 < klen) {   // prefetch next tile during compute
            const int kn = k0 + kc + 16;
            const float* xp = &X[(size_t)(rb + lr) * DIM + kn + lk];
            a0 = *(const float4*)xp;
            a1 = *(const float4*)(xp + 4);
            float4 c0 = *(const float4*)&bias[kn + lk];
            float4 c1 = *(const float4*)&bias[kn + lk + 4];
            a0.x += c0.x; a0.y += c0.y; a0.z += c0.z; a0.w += c0.w;
            a1.x += c1.x; a1.y += c1.y; a1.z += c1.z; a1.w += c1.w;
            b0 = *(const float4*)&W[(size_t)(kn + bk) * PDIM + cb + bc];
            b1 = *(const float4*)&W[(size_t)(kn + bk) * PDIM + cb + bc + 4];
        }
        #pragma unroll
        for (int k = 0; k < 16; ++k) {
            float4 x0 = *(const float4*)&As[k][ry * 8];
            float4 x1 = *(const float4*)&As[k][ry * 8 + 4];
            float4 y0 = *(const float4*)&Bs[k][rx * 8];
            float4 y1 = *(const float4*)&Bs[k][rx * 8 + 4];
            float aa[8] = {x0.x, x0.y, x0.z, x0.w, x1.x, x1.y, x1.z, x1.w};
            float bb[8] = {y0.x, y0.y, y0.z, y0.w, y1.x, y1.y, y1.z, y1.w};
            #pragma unroll
            for (int i = 0; i < 8; ++i)
                #pragma unroll
                for (int j = 0; j < 8; ++j)
                    acc[i][j] = fmaf(aa[i], bb[j], acc[i][j]);
        }
        __syncthreads();
    }
    #pragma unroll
    for (int i = 0; i < 8; ++i) {
        const size_t base = (size_t)(rb + ry * 8 + i) * PDIM + cb + rx * 8;
        *(float4*)&dst[base]     = make_float4(acc[i][0], acc[i][1], acc[i][2], acc[i][3]);
        *(float4*)&dst[base + 4] = make_float4(acc[i][4], acc[i][5], acc[i][6], acc[i][7]);
    }
    if (do_xn) {
        xsum += __shfl_xor(xsum, 1);   // lanes 2m,2m+1 share row lr
        if ((t & 1) == 0) atomicAdd(&xn2[rb + lr], xsum);
    }
}

// exact fold: proj = rn(rn(S0 + S1) + S2)   (in-place on the S0 buffer)
__global__ __launch_bounds__(256) void k_combine(const float* __restrict__ S1,
                                                 const float* __restrict__ S2,
                                                 float* __restrict__ P) {
    int e = blockIdx.x * 256 + threadIdx.x;   // float4 index
    float4 s0 = ((const float4*)P)[e];
    float4 s1 = ((const float4*)S1)[e];
    float4 s2 = ((const float4*)S2)[e];
    float4 r;
    r.x = __fadd_rn(__fadd_rn(s0.x, s1.x), s2.x);
    r.y = __fadd_rn(__fadd_rn(s0.y, s1.y), s2.y);
    r.z = __fadd_rn(__fadd_rn(s0.z, s1.z), s2.z);
    r.w = __fadd_rn(__fadd_rn(s0.w, s1.w), s2.w);
    ((float4*)P)[e] = r;
}

// ============================================================================
// K_pm: PM = proj @ M  (M = W^T W), K=256. Tolerant path. 128x128/8x8.
// ============================================================================
__global__ __launch_bounds__(256) void k_pm(const float* __restrict__ P,
                                            const float* __restrict__ M,
                                            float* __restrict__ PM) {
    __shared__ float As[16][128];
    __shared__ float Bs[16][128];
    const int t = threadIdx.x;
    const int ry = t >> 4;
    const int rx = t & 15;
    const int rb = blockIdx.y * 128;
    const int cb = blockIdx.x * 128;
    const int lr = t >> 1;
    const int lk = (t & 1) * 8;
    const int bk = t >> 4;
    const int bc = (t & 15) * 8;
    float acc[8][8] = {};
    for (int kc = 0; kc < PDIM; kc += 16) {
        float4 a0 = *(const float4*)&P[(size_t)(rb + lr) * PDIM + kc + lk];
        float4 a1 = *(const float4*)&P[(size_t)(rb + lr) * PDIM + kc + lk + 4];
        float4 b0 = *(const float4*)&M[(size_t)(kc + bk) * PDIM + cb + bc];
        float4 b1 = *(const float4*)&M[(size_t)(kc + bk) * PDIM + cb + bc + 4];
        As[lk + 0][lr] = a0.x; As[lk + 1][lr] = a0.y; As[lk + 2][lr] = a0.z; As[lk + 3][lr] = a0.w;
        As[lk + 4][lr] = a1.x; As[lk + 5][lr] = a1.y; As[lk + 6][lr] = a1.z; As[lk + 7][lr] = a1.w;
        *(float4*)&Bs[bk][bc] = b0;
        *(float4*)&Bs[bk][bc + 4] = b1;
        __syncthreads();
        #pragma unroll
        for (int k = 0; k < 16; ++k) {
            float4 x0 = *(const float4*)&As[k][ry * 8];
            float4 x1 = *(const float4*)&As[k][ry * 8 + 4];
            float4 y0 = *(const float4*)&Bs[k][rx * 8];
            float4 y1 = *(const float4*)&Bs[k][rx * 8 + 4];
            float aa[8] = {x0.x, x0.y, x0.z, x0.w, x1.x, x1.y, x1.z, x1.w};
            float bb[8] = {y0.x, y0.y, y0.z, y0.w, y1.x, y1.y, y1.z, y1.w};
            #pragma unroll
            for (int i = 0; i < 8; ++i)
                #pragma unroll
                for (int j = 0; j < 8; ++j)
                    acc[i][j] = fmaf(aa[i], bb[j], acc[i][j]);
        }
        __syncthreads();
    }
    #pragma unroll
    for (int i = 0; i < 8; ++i) {
        const size_t base = (size_t)(rb + ry * 8 + i) * PDIM + cb + rx * 8;
        *(float4*)&PM[base]     = make_float4(acc[i][0], acc[i][1], acc[i][2], acc[i][3]);
        *(float4*)&PM[base + 4] = make_float4(acc[i][4], acc[i][5], acc[i][6], acc[i][7]);
    }
}

// ============================================================================
// K_wtw: M[256][256] = W^T W  (K=1024). 64x64 tile, 4x4 micro, grid (4,4).
// ============================================================================
__global__ __launch_bounds__(256) void k_wtw(const float* __restrict__ W,
                                             float* __restrict__ M) {
    __shared__ float As[16][64];
    __shared__ float Bs[16][64];
    const int t = threadIdx.x;
    const int tx = t & 15, ty = t >> 4;
    const int ib = blockIdx.x * 64;
    const int jb = blockIdx.y * 64;
    const int sk = t >> 4;
    const int sc = (t & 15) * 4;
    float acc[4][4] = {};
    for (int kc = 0; kc < DIM; kc += 16) {
        float4 a = *(const float4*)&W[(size_t)(kc + sk) * PDIM + ib + sc];
        float4 b = *(const float4*)&W[(size_t)(kc + sk) * PDIM + jb + sc];
        *(float4*)&As[sk][sc] = a;
        *(float4*)&Bs[sk][sc] = b;
        __syncthreads();
        #pragma unroll
        for (int k = 0; k < 16; ++k) {
            float4 a4 = *(const float4*)&As[k][ty * 4];
            float4 b4 = *(const float4*)&Bs[k][tx * 4];
            float aa[4] = {a4.x, a4.y, a4.z, a4.w};
            float bb[4] = {b4.x, b4.y, b4.z, b4.w};
            #pragma unroll
            for (int i = 0; i < 4; ++i)
                #pragma unroll
                for (int j = 0; j < 4; ++j)
                    acc[i][j] = fmaf(aa[i], bb[j], acc[i][j]);
        }
        __syncthreads();
    }
    #pragma unroll
    for (int i = 0; i < 4; ++i)
        #pragma unroll
        for (int j = 0; j < 4; ++j)
            M[(size_t)(ib + ty * 4 + i) * PDIM + jb + tx * 4 + j] = acc[i][j];
}

// rowres[n] = xn2[n] + sum_c P[n][c]*(PM[n][c] - 2*P[n][c])
__global__ __launch_bounds__(256) void k_rowres(const float* __restrict__ P,
                                                const float* __restrict__ PM,
                                                const float* __restrict__ xn2,
                                                float* __restrict__ rowres) {
    const int n = blockIdx.x * 4 + (threadIdx.x >> 6);
    const int lane = threadIdx.x & 63;
    float4 p  = *(const float4*)&P[(size_t)n * PDIM + lane * 4];
    float4 pm = *(const float4*)&PM[(size_t)n * PDIM + lane * 4];
    float s = 0.0f;
    s = fmaf(p.x, pm.x - 2.0f * p.x, s);
    s = fmaf(p.y, pm.y - 2.0f * p.y, s);
    s = fmaf(p.z, pm.z - 2.0f * p.z, s);
    s = fmaf(p.w, pm.w - 2.0f * p.w, s);
    #pragma unroll
    for (int o = 1; o < 64; o <<= 1) s += __shfl_xor(s, o);
    if (lane == 0) rowres[n] = xn2[n] + s;
}

// ============================================================================
// K2: cov += P^T P (fp32, split-K, atomicAdd) — tolerant
// ============================================================================
__global__ __launch_bounds__(256) void k_cov(const float* __restrict__ Pm,
                                             float* __restrict__ cov) {
    __shared__ float As[16][64];
    __shared__ float Bs[16][64];
    const int t = threadIdx.x;
    const int tx = t & 15, ty = t >> 4;
    const int ib = blockIdx.x * 64;
    const int jb = blockIdx.y * 64;
    const int nb = blockIdx.z * 2048;
    const int sk = t >> 4;
    const int sc = (t & 15) * 4;
    float acc[4][4] = {};
    for (int kc = 0; kc < 2048; kc += 16) {
        float4 a = *(const float4*)&Pm[(size_t)(nb + kc + sk) * PDIM + ib + sc];
        float4 b = *(const float4*)&Pm[(size_t)(nb + kc + sk) * PDIM + jb + sc];
        *(float4*)&As[sk][sc] = a;
        *(float4*)&Bs[sk][sc] = b;
        __syncthreads();
        #pragma unroll
        for (int k = 0; k < 16; ++k) {
            float4 a4 = *(const float4*)&As[k][ty * 4];
            float4 b4 = *(const float4*)&Bs[k][tx * 4];
            float aa[4] = {a4.x, a4.y, a4.z, a4.w};
            float bb[4] = {b4.x, b4.y, b4.z, b4.w};
            #pragma unroll
            for (int i = 0; i < 4; ++i)
                #pragma unroll
                for (int j = 0; j < 4; ++j)
                    acc[i][j] = fmaf(aa[i], bb[j], acc[i][j]);
        }
        __syncthreads();
    }
    #pragma unroll
    for (int i = 0; i < 4; ++i)
        #pragma unroll
        for (int j = 0; j < 4; ++j)
            atomicAdd(&cov[(size_t)(ib + ty * 4 + i) * PDIM + jb + tx * 4 + j], acc[i][j]);
}

__global__ __launch_bounds__(256) void k_covloss(const float* __restrict__ cov,
                                                 float* __restrict__ scal) {
    const int t = threadIdx.x;
    float s = 0.0f;
    for (int e = t; e < PDIM * PDIM; e += 256) {
        int i = e >> 8, j = e & 255;
        float v = cov[e] * (1.0f / 32768.0f) - (i == j ? 1.0f : 0.0f);
        s = fmaf(v, v, s);
    }
    #pragma unroll
    for (int o = 1; o < 64; o <<= 1) s += __shfl_xor(s, o);
    __shared__ float r4[4];
    if ((t & 63) == 0) r4[t >> 6] = s;
    __syncthreads();
    if (t == 0) scal[1] = (r4[0] + r4[1] + r4[2] + r4[3]) * (1.0f / 65536.0f);
}

// l2 sum: scal[0] += sum over rows of sqrt(rowres)
__global__ __launch_bounds__(256) void k_l2(const float* __restrict__ rowres,
                                            float* __restrict__ scal) {
    int r = blockIdx.x * 256 + threadIdx.x;
    float v = sqrtf(rowres[r]);
    #pragma unroll
    for (int o = 1; o < 64; o <<= 1) v += __shfl_xor(v, o);
    if ((threadIdx.x & 63) == 0) atomicAdd(&scal[0], v);
}

// cnorm: numpy pairwise (8-acc) order, exact
__global__ __launch_bounds__(256) void k_cnorm(const float* __restrict__ cbs,
                                               float* __restrict__ cnorm) {
    int c = blockIdx.x * 256 + threadIdx.x;
    const float* p = &cbs[(size_t)c * SECD];
    float a[8];
    #pragma unroll
    for (int j = 0; j < 8; ++j) a[j] = __fmul_rn(p[j], p[j]);
    #pragma unroll
    for (int i = 8; i < 64; i += 8)
        #pragma unroll
        for (int j = 0; j < 8; ++j)
            a[j] = __fadd_rn(a[j], __fmul_rn(p[i + j], p[i + j]));
    float r = __fadd_rn(__fadd_rn(__fadd_rn(a[0], a[1]), __fadd_rn(a[2], a[3])),
                        __fadd_rn(__fadd_rn(a[4], a[5]), __fadd_rn(a[6], a[7])));
    cnorm[c] = r;
}

// ============================================================================
// K4: VQ, exact argmin. 64 rows/block, ct tiles of 128 codes, 8x4 micro.
// ============================================================================
__global__ __launch_bounds__(256) void k_vq(const float* __restrict__ proj,
                                            const float* __restrict__ cbs,
                                            const float* __restrict__ cnorm,
                                            int* __restrict__ widx,
                                            float* __restrict__ out_idx,
                                            float* __restrict__ out_qloss) {
    __shared__ float xs[64][64];    // xs[k][row]   16 KB
    __shared__ float cs[64][128];   // cs[k][code]  32 KB
    __shared__ float xnorm[64];
    __shared__ int   sidx[64];
    const int t = threadIdx.x;
    const int ry = t >> 5;          // rows ry*8..+7
    const int tx = t & 31;          // codes tx*4..+3 within ct tile
    const int rb = blockIdx.x * 64;
    const int lr = t >> 2;          // staging/qloss row 0..63
    const int kq = (t & 3) * 16;    // staging k slab
    const int cr = t >> 1;          // cs staging code 0..127
    const int ko = (t & 1) * 32;    // cs staging k offset
    float qacc[16];
    #pragma unroll
    for (int i = 0; i < 16; ++i) qacc[i] = 0.0f;

    for (int s = 0; s < NSEC; ++s) {
        #pragma unroll
        for (int i = 0; i < 16; i += 4) {
            float4 v = *(const float4*)&proj[(size_t)(rb + lr) * PDIM + s * SECD + kq + i];
            xs[kq + i + 0][lr] = v.x; xs[kq + i + 1][lr] = v.y;
            xs[kq + i + 2][lr] = v.z; xs[kq + i + 3][lr] = v.w;
        }
        __syncthreads();
        if (t < 64) {   // numpy pairwise_sum(64): 8 accumulators, no fma
            float a[8];
            #pragma unroll
            for (int j = 0; j < 8; ++j) { float v = xs[j][t]; a[j] = __fmul_rn(v, v); }
            #pragma unroll
            for (int i = 8; i < 64; i += 8)
                #pragma unroll
                for (int j = 0; j < 8; ++j) {
                    float v = xs[i + j][t];
                    a[j] = __fadd_rn(a[j], __fmul_rn(v, v));
                }
            xnorm[t] = __fadd_rn(__fadd_rn(__fadd_rn(a[0], a[1]), __fadd_rn(a[2], a[3])),
                                 __fadd_rn(__fadd_rn(a[4], a[5]), __fadd_rn(a[6], a[7])));
        }
        float best[8]; int bidx[8];
        #pragma unroll
        for (int i = 0; i < 8; ++i) { best[i] = 3.4e38f; bidx[i] = 0; }

        for (int ct = 0; ct < 8; ++ct) {
            __syncthreads();   // cs reuse guard; publishes xnorm at ct==0
            #pragma unroll
            for (int u = 0; u < 32; u += 4) {
                float4 v = *(const float4*)&cbs[(size_t)(s * NCODE + ct * 128 + cr) * SECD + ko + u];
                cs[ko + u + 0][cr] = v.x; cs[ko + u + 1][cr] = v.y;
                cs[ko + u + 2][cr] = v.z; cs[ko + u + 3][cr] = v.w;
            }
            __syncthreads();
            float4 cn4 = *(const float4*)&cnorm[s * NCODE + ct * 128 + tx * 4];
            float cna[4] = {cn4.x, cn4.y, cn4.z, cn4.w};
            float acc[8][4] = {};
            #pragma unroll 8
            for (int k = 0; k < 64; ++k) {
                float4 x0 = *(const float4*)&xs[k][ry * 8];
                float4 x1 = *(const float4*)&xs[k][ry * 8 + 4];
                float4 b4 = *(const float4*)&cs[k][tx * 4];
                float aa[8] = {x0.x, x0.y, x0.z, x0.w, x1.x, x1.y, x1.z, x1.w};
                float bb[4] = {b4.x, b4.y, b4.z, b4.w};
                #pragma unroll
                for (int i = 0; i < 8; ++i)
                    #pragma unroll
                    for (int j = 0; j < 4; ++j)
                        acc[i][j] = fmaf(aa[i], bb[j], acc[i][j]);
            }
            #pragma unroll
            for (int i = 0; i < 8; ++i) {
                float xn = xnorm[ry * 8 + i];
                #pragma unroll
                for (int j = 0; j < 4; ++j) {
                    float d = __fadd_rn(__fsub_rn(xn, __fmul_rn(2.0f, acc[i][j])), cna[j]);
                    int code = ct * 128 + tx * 4 + j;
                    if (d < best[i]) { best[i] = d; bidx[i] = code; }
                }
            }
        }
        // lexicographic (dist, idx) min across the 32 tx lanes per row
        #pragma unroll
        for (int i = 0; i < 8; ++i) {
            float d = best[i]; int ix = bidx[i];
            #pragma unroll
            for (int o = 1; o < 32; o <<= 1) {
                float od = __shfl_xor(d, o);
                int   oi = __shfl_xor(ix, o);
                if (od < d || (od == d && oi < ix)) { d = od; ix = oi; }
            }
            if (tx == 0) {
                int row = rb + ry * 8 + i;
                widx[s * NROW + row] = ix;
                out_idx[s * NROW + row] = (float)ix;
                sidx[ry * 8 + i] = ix;
            }
        }
        __syncthreads();
        {   // accumulate (q - x)^2 for this section (register accumulators)
            const float* crow = &cbs[(size_t)(s * NCODE + sidx[lr]) * SECD];
            #pragma unroll
            for (int i = 0; i < 16; i += 4) {
                float4 q = *(const float4*)&crow[kq + i];
                float qq[4] = {q.x, q.y, q.z, q.w};
                #pragma unroll
                for (int u = 0; u < 4; ++u) {
                    float d = qq[u] - xs[kq + i + u][lr];
                    qacc[i + u] = fmaf(d, d, qacc[i + u]);
                }
            }
        }
        __syncthreads();   // xs reuse guard for next section
    }
    #pragma unroll
    for (int i = 0; i < 16; i += 4) {
        float4 v = make_float4(0.25f * qacc[i + 0], 0.25f * qacc[i + 1],
                               0.25f * qacc[i + 2], 0.25f * qacc[i + 3]);
        *(float4*)&out_qloss[(size_t)(rb + lr) * SECD + kq + i] = v;
    }
}

// ============================================================================
// K5: CbU[s][c][d] = sum_k Cb[s][c][k] * W[d][s*64+k]
// ============================================================================
__global__ __launch_bounds__(256) void k_cbu(const float* __restrict__ cbs,
                                             const float* __restrict__ W,
                                             float* __restrict__ cbu) {
    __shared__ float As[16][64];
    __shared__ float Bs[16][64];
    const int t = threadIdx.x;
    const int tx = t & 15, ty = t >> 4;
    const int s = blockIdx.z;
    const int cbase = blockIdx.y * 64;
    const int db = blockIdx.x * 64;
    const int lr = t >> 2;
    const int lk = (t & 3) * 4;
    float acc[4][4] = {};
    for (int kc = 0; kc < SECD; kc += 16) {
        float4 a = *(const float4*)&cbs[(size_t)(s * NCODE + cbase + lr) * SECD + kc + lk];
        float4 b = *(const float4*)&W[(size_t)(db + lr) * PDIM + s * SECD + kc + lk];
        As[lk + 0][lr] = a.x; As[lk + 1][lr] = a.y;
        As[lk + 2][lr] = a.z; As[lk + 3][lr] = a.w;
        Bs[lk + 0][lr] = b.x; Bs[lk + 1][lr] = b.y;
        Bs[lk + 2][lr] = b.z; Bs[lk + 3][lr] = b.w;
        __syncthreads();
        #pragma unroll
        for (int k = 0; k < 16; ++k) {
            float4 a4 = *(const float4*)&As[k][ty * 4];
            float4 b4 = *(const float4*)&Bs[k][tx * 4];
            float aa[4] = {a4.x, a4.y, a4.z, a4.w};
            float bb[4] = {b4.x, b4.y, b4.z, b4.w};
            #pragma unroll
            for (int i = 0; i < 4; ++i)
                #pragma unroll
                for (int j = 0; j < 4; ++j)
                    acc[i][j] = fmaf(aa[i], bb[j], acc[i][j]);
        }
        __syncthreads();
    }
    #pragma unroll
    for (int i = 0; i < 4; ++i) {
        float4 v = make_float4(acc[i][0], acc[i][1], acc[i][2], acc[i][3]);
        *(float4*)&cbu[(size_t)(s * NCODE + cbase + ty * 4 + i) * DIM + db + tx * 4] = v;
    }
}

// K6: out0[n][d] = sum_s CbU[s][idx[s][n]][d] - bias[d]
__global__ __launch_bounds__(256) void k_gather(const float* __restrict__ cbu,
                                                const int* __restrict__ widx,
                                                const float* __restrict__ bias,
                                                float* __restrict__ out0) {
    const int n = blockIdx.x;
    const int d = threadIdx.x * 4;
    int i0 = widx[0 * NROW + n];
    int i1 = widx[1 * NROW + n];
    int i2 = widx[2 * NROW + n];
    int i3 = widx[3 * NROW + n];
    float4 v0 = *(const float4*)&cbu[((size_t)(0 * NCODE + i0)) * DIM + d];
    float4 v1 = *(const float4*)&cbu[((size_t)(1 * NCODE + i1)) * DIM + d];
    float4 v2 = *(const float4*)&cbu[((size_t)(2 * NCODE + i2)) * DIM + d];
    float4 v3 = *(const float4*)&cbu[((size_t)(3 * NCODE + i3)) * DIM + d];
    float4 b = *(const float4*)&bias[d];
    float4 r;
    r.x = v0.x + v1.x + v2.x + v3.x - b.x;
    r.y = v0.y + v1.y + v2.y + v3.y - b.y;
    r.z = v0.z + v1.z + v2.z + v3.z - b.z;
    r.w = v0.w + v1.w + v2.w + v3.w - b.w;
    *(float4*)&out0[(size_t)n * DIM + d] = r;
}

__global__ __launch_bounds__(256) void k_addpca(float* __restrict__ out1,
                                                const float* __restrict__ scal) {
    float pca = scal[0] * (1.0f / 32768.0f) + scal[1];
    int e = blockIdx.x * 256 + threadIdx.x;
    float4* p = (float4*)out1;
    float4 v = p[e];
    v.x += pca; v.y += pca; v.z += pca; v.w += pca;
    p[e] = v;
}

__global__ __launch_bounds__(256) void k_tail(const float* __restrict__ cbs,
                                              float* __restrict__ out3,
                                              float* __restrict__ out4) {
    int e = blockIdx.x * 256 + threadIdx.x;
    ((float4*)out3)[e] = ((const float4*)cbs)[e];
    if (e < 4096) out4[e] = 1.0f;
}

extern "C" void kernel_launch(void* const* d_in, const int* in_sizes, int n_in,
                              void* d_out, int out_size, void* d_ws, size_t ws_size,
                              hipStream_t stream) {
    (void)in_sizes; (void)n_in; (void)out_size; (void)ws_size;
    const float* X    = (const float*)d_in[0];   // [32768,1024]
    const float* W    = (const float*)d_in[1];   // [1024,256]
    const float* bias = (const float*)d_in[2];   // [1024]
    const float* cbs  = (const float*)d_in[3];   // [4,1024,64]

    float* out  = (float*)d_out;
    float* out0 = out;                 // quantized [32768,1024]
    float* out1 = out + 33554432;      // qloss [32768,64]
    float* out2 = out + 35651584;      // nn_idx as float [4,32768]
    float* out3 = out + 35782656;      // codebook copy [4096,64]
    float* out4 = out + 36044800;      // cluster_counts ones [4,1024]

    char* ws = (char*)d_ws;
    float* cbu    = (float*)(ws);                  // 16777216 B
    float* rowres = (float*)(ws + 16777216);       //   131072 B
    float* cov    = (float*)(ws + 16908288);       //   262144 B
    float* scal   = (float*)(ws + 17170432);       //       64 B
    float* xn2    = (float*)(ws + 17170496);       //   131072 B
    float* cnorm  = (float*)(ws + 17301568);       //    16384 B
    int*   widx   = (int*)  (ws + 17317952);       //   524288 B
    float* wtw    = (float*)(ws + 17842240);       //   262144 B (M = W^T W)

    // scratch inside the out0 region (33,554,432 floats; dead before k_gather):
    float* proj = out0;                 // 8,388,608 floats (S0, then combined)
    float* S1   = out0 + 8388608;       // 8,388,608 floats
    float* S2   = out0 + 16777216;      // 8,388,608 floats
    float* PM   = out0 + 25165824;      // 8,388,608 floats

    // zero cov + scal + xn2 (contiguous)
    hipMemsetAsync(ws + 16908288, 0, 262144 + 64 + 131072, stream);

    k_proj_split<<<dim3(2, 256, 3), 256, 0, stream>>>(X, W, bias, proj, S1, S2, xn2);
    k_combine   <<<8192,            256, 0, stream>>>(S1, S2, proj);
    k_wtw       <<<dim3(4, 4),      256, 0, stream>>>(W, wtw);
    k_cov       <<<dim3(4, 4, 16),  256, 0, stream>>>(proj, cov);
    k_covloss   <<<1,               256, 0, stream>>>(cov, scal);
    k_pm        <<<dim3(2, 256),    256, 0, stream>>>(proj, wtw, PM);
    k_rowres    <<<8192,            256, 0, stream>>>(proj, PM, xn2, rowres);
    k_l2        <<<128,             256, 0, stream>>>(rowres, scal);
    k_cnorm     <<<16,              256, 0, stream>>>(cbs, cnorm);
    k_vq        <<<512,             256, 0, stream>>>(proj, cbs, cnorm, widx, out2, out1);
    k_cbu       <<<dim3(16, 16, 4), 256, 0, stream>>>(cbs, W, cbu);
    k_gather    <<<32768,           256, 0, stream>>>(cbu, widx, bias, out0);
    k_addpca    <<<2048,            256, 0, stream>>>(out1, scal);
    k_tail      <<<256,             256, 0, stream>>>(cbs, out3, out4);
}